// Round 1
// baseline (507.841 us; speedup 1.0000x reference)
//
#include <hip/hip_runtime.h>
#include <stdint.h>

#define NUM_HEADS 16
#define HIDDEN    2048
#define HEAD_SIZE 128
#define ROT_DIM   32
#define TOTAL     4096
#define SEQ       1024
#define QKV_N     (3*HIDDEN)   // 6144

typedef __bf16 bf16x8 __attribute__((ext_vector_type(8)));
typedef float  f32x4  __attribute__((ext_vector_type(4)));

__device__ __forceinline__ unsigned short f2bf(float f) {
  unsigned u = __float_as_uint(f);
  u += 0x7FFFu + ((u >> 16) & 1u);          // RNE
  return (unsigned short)(u >> 16);
}
__device__ __forceinline__ float bf2f(unsigned short h) {
  return __uint_as_float(((unsigned)h) << 16);
}
// async global->LDS, 16B per lane. LDS dest must be wave-uniform base + lane*16.
__device__ __forceinline__ void cp16(void* lds, const void* g) {
  __builtin_amdgcn_global_load_lds(
      (const __attribute__((address_space(1))) void*)g,
      (__attribute__((address_space(3))) void*)lds, 16, 0, 0);
}

// ---------------------------------------------------------------- convert
__global__ __launch_bounds__(256) void f32_to_bf16_k(
    const float* __restrict__ in, unsigned short* __restrict__ out, int n)
{
  int i = (blockIdx.x * 256 + threadIdx.x) * 4;
  if (i >= n) return;
  float4 v = *(const float4*)(in + i);
  unsigned p0 = (unsigned)f2bf(v.x) | ((unsigned)f2bf(v.y) << 16);
  unsigned p1 = (unsigned)f2bf(v.z) | ((unsigned)f2bf(v.w) << 16);
  uint2 pk; pk.x = p0; pk.y = p1;
  *(uint2*)(out + i) = pk;
}

// ---------------------------------------------------------------- GEMM (B^T input)
// C[i,j] = sum_k A[i,k]*B[j,k] + bias[j]
// MODE 0: write float32 to Cf[row*N+col]
// MODE 1: scatter bf16 into Qb/Kb/Vb [B,H,S,D] (col -> head/qkv/dim)
template <int MODE>
__global__ __launch_bounds__(256) void gemm_bt(
    const unsigned short* __restrict__ A,   // [M][K] bf16
    const unsigned short* __restrict__ B,   // [N][K] bf16
    const float* __restrict__ bias,         // [N]
    float* __restrict__ Cf,
    unsigned short* __restrict__ Qb,
    unsigned short* __restrict__ Kb,
    unsigned short* __restrict__ Vb,
    int M, int N, int K)
{
  __shared__ unsigned short lsA[128*32];    // 8 KB, row pitch 64B (m97 layout)
  __shared__ unsigned short lsB[128*32];
  const int tid  = threadIdx.x;
  const int w    = tid >> 6, lane = tid & 63;
  const int quad = lane >> 4, lm = lane & 15;
  const int wm   = w & 1, wn = w >> 1;
  const int mBase = blockIdx.y * 128;
  const int nBase = blockIdx.x * 128;

  const f32x4 zero4 = {0.f, 0.f, 0.f, 0.f};
  f32x4 acc[4][4];
#pragma unroll
  for (int i = 0; i < 4; i++)
#pragma unroll
    for (int j = 0; j < 4; j++) acc[i][j] = zero4;

  for (int k0 = 0; k0 < K; k0 += 32) {
#pragma unroll
    for (int i = 0; i < 2; i++) {           // stage A: 128 rows x 64B
      int off = i * 4096 + tid * 16;
      int row = off >> 6, colb = off & 63;
      cp16((char*)lsA + off, (const char*)(A + (size_t)(mBase + row) * K + k0) + colb);
    }
#pragma unroll
    for (int i = 0; i < 2; i++) {           // stage B
      int off = i * 4096 + tid * 16;
      int row = off >> 6, colb = off & 63;
      cp16((char*)lsB + off, (const char*)(B + (size_t)(nBase + row) * K + k0) + colb);
    }
    __syncthreads();                         // drains vmcnt -> LDS visible
    bf16x8 af[4], bfr[4];
#pragma unroll
    for (int mf = 0; mf < 4; mf++)
      af[mf] = *(const bf16x8*)(lsA + (wm * 64 + mf * 16 + lm) * 32 + quad * 8);
#pragma unroll
    for (int nf = 0; nf < 4; nf++)
      bfr[nf] = *(const bf16x8*)(lsB + (wn * 64 + nf * 16 + lm) * 32 + quad * 8);
#pragma unroll
    for (int mf = 0; mf < 4; mf++)
#pragma unroll
      for (int nf = 0; nf < 4; nf++)
        acc[mf][nf] = __builtin_amdgcn_mfma_f32_16x16x32_bf16(af[mf], bfr[nf], acc[mf][nf], 0, 0, 0);
    __syncthreads();
  }

  // epilogue: C layout col=lane&15, row=quad*4+r (m89-verified)
#pragma unroll
  for (int nf = 0; nf < 4; nf++) {
    int col = nBase + wn * 64 + nf * 16 + lm;
    float bv = bias[col];
    if (MODE == 0) {
#pragma unroll
      for (int mf = 0; mf < 4; mf++) {
        int row0 = mBase + wm * 64 + mf * 16 + quad * 4;
#pragma unroll
        for (int r = 0; r < 4; r++)
          Cf[(size_t)(row0 + r) * N + col] = acc[mf][nf][r] + bv;
      }
    } else {
      int chunk = col >> 7;                  // 128-col chunk = one (head, q/k/v)
      int hh = chunk / 3, t = chunk - 3 * hh;
      int d = col & 127;
      unsigned short* dst = (t == 0) ? Qb : (t == 1) ? Kb : Vb;
#pragma unroll
      for (int mf = 0; mf < 4; mf++) {
        int row0 = mBase + wm * 64 + mf * 16 + quad * 4;
#pragma unroll
        for (int r = 0; r < 4; r++) {
          int row = row0 + r;
          int b = row >> 10, s = row & 1023;
          dst[((size_t)(b * NUM_HEADS + hh) * SEQ + s) * HEAD_SIZE + d] = f2bf(acc[mf][nf][r] + bv);
        }
      }
    }
  }
}

// ---------------------------------------------------------------- rotary (in place on Q,K)
// one thread per (q/k, bh, s, freq i): owns pair (d=i, d=i+16) -> race-free in place
__global__ __launch_bounds__(256) void rotary_k(
    unsigned short* __restrict__ Qb, unsigned short* __restrict__ Kb,
    const int* __restrict__ pos_ids)
{
  int f = blockIdx.x * 256 + threadIdx.x;    // 2*64*1024*16 = 2^21 threads
  int qk   = f >> 20;
  int rem  = f & 0xFFFFF;
  int bh   = rem >> 14;
  int rem2 = rem & 0x3FFF;
  int s    = rem2 >> 4;
  int i    = rem2 & 15;
  int b    = bh >> 4;
  float pos = (float)pos_ids[b * SEQ + s];
  float inv = exp2f(-0.8304820237f * (float)i);   // 10000^(-i/16)
  float ang = pos * inv, sn, c;
  sincosf(ang, &sn, &c);
  unsigned short* p = (qk ? Kb : Qb) + ((size_t)bh * SEQ + s) * HEAD_SIZE;
  float x1 = bf2f(p[i]);
  float x2 = bf2f(p[i + 16]);
  p[i]      = f2bf(x1 * c - x2 * sn);
  p[i + 16] = f2bf(x1 * sn + x2 * c);
}

// ---------------------------------------------------------------- flash attention
// grid (16 qtiles, 64 bh), 256 threads = 4 waves, wave w owns q-rows w*16..w*16+15
__global__ __launch_bounds__(256) void flash_attn_k(
    const unsigned short* __restrict__ Q,
    const unsigned short* __restrict__ K,
    const unsigned short* __restrict__ V,
    unsigned short* __restrict__ O)          // [TOTAL][HIDDEN] bf16
{
  const int qt = blockIdx.x;
  const int bh = blockIdx.y;
  const int b = bh >> 4, h = bh & 15;
  const size_t base = (size_t)bh * SEQ * HEAD_SIZE;
  const unsigned short* Qp = Q + base;
  const unsigned short* Kp = K + base;
  const unsigned short* Vp = V + base;

  __shared__ unsigned short Ks[4][64][32];   // [kchunk][s][d32], 64B pitch (load_lds-compatible)
  __shared__ unsigned short Vt[128][72];     // V^T [d][s], pitch 144B (pad kills bank conflict)
  __shared__ unsigned short Ps[64][72];      // P [qlocal][s], pitch 144B

  const int tid  = threadIdx.x;
  const int w    = tid >> 6, lane = tid & 63;
  const int quad = lane >> 4, lm = lane & 15;

  bf16x8 qf[4];
  {
    const unsigned short* qrow = Qp + (size_t)(qt * 64 + w * 16 + lm) * HEAD_SIZE;
#pragma unroll
    for (int kk = 0; kk < 4; kk++)
      qf[kk] = *(const bf16x8*)(qrow + kk * 32 + quad * 8);
  }
  float m_r[4], l_r[4];
#pragma unroll
  for (int r = 0; r < 4; r++) { m_r[r] = -1e30f; l_r[r] = 0.f; }
  const f32x4 zero4 = {0.f, 0.f, 0.f, 0.f};
  f32x4 o[8];
#pragma unroll
  for (int i = 0; i < 8; i++) o[i] = zero4;

  const float K1 = 0.1275156876f;            // (1/sqrt(128)) * log2(e)

  for (int kt = 0; kt <= qt; ++kt) {
    // stage K tile (64x128) via global_load_lds, 4 kchunks of 32 cols
#pragma unroll
    for (int kk = 0; kk < 4; kk++) {
      const char* g = (const char*)(Kp + (size_t)(kt * 64 + (tid >> 2)) * HEAD_SIZE + kk * 32)
                      + (tid & 3) * 16;
      cp16((char*)&Ks[kk][0][0] + tid * 16, g);
    }
    // stage V^T with transpose (pack 2 rows -> b32 LDS writes)
#pragma unroll
    for (int t2 = 0; t2 < 2; t2++) {
      int task = tid + t2 * 256;
      int sp = task & 31, dc = task >> 5;    // s pair, d-chunk of 8
      const unsigned short* vs = Vp + (size_t)(kt * 64 + sp * 2) * HEAD_SIZE + dc * 8;
      uint4 r0 = *(const uint4*)vs;
      uint4 r1 = *(const uint4*)(vs + HEAD_SIZE);
      const unsigned short* a0 = (const unsigned short*)&r0;
      const unsigned short* a1 = (const unsigned short*)&r1;
#pragma unroll
      for (int j = 0; j < 8; j++) {
        unsigned wrd = (unsigned)a0[j] | ((unsigned)a1[j] << 16);
        *(unsigned*)&Vt[dc * 8 + j][sp * 2] = wrd;
      }
    }
    __syncthreads();

    // S = Q K^T  (raw scores; scale folded into exp2 constant)
    f32x4 sf[4];
#pragma unroll
    for (int nf = 0; nf < 4; nf++) {
      f32x4 accs = zero4;
#pragma unroll
      for (int kk = 0; kk < 4; kk++) {
        bf16x8 kfrag = *(const bf16x8*)(&Ks[kk][nf * 16 + lm][quad * 8]);
        accs = __builtin_amdgcn_mfma_f32_16x16x32_bf16(qf[kk], kfrag, accs, 0, 0, 0);
      }
      sf[nf] = accs;
    }
    int qrow0 = qt * 64 + w * 16 + quad * 4;
    if (kt == qt) {
#pragma unroll
      for (int nf = 0; nf < 4; nf++) {
        int col = kt * 64 + nf * 16 + lm;
#pragma unroll
        for (int r = 0; r < 4; r++)
          if (col > qrow0 + r) sf[nf][r] = -1e30f;
      }
    }
    // online softmax: rows of a quad are quad*4+r, reduce across 16 lanes
    float alpha[4], psum[4];
#pragma unroll
    for (int r = 0; r < 4; r++) {
      float v = fmaxf(fmaxf(sf[0][r], sf[1][r]), fmaxf(sf[2][r], sf[3][r]));
      v = fmaxf(v, __shfl_xor(v, 1));
      v = fmaxf(v, __shfl_xor(v, 2));
      v = fmaxf(v, __shfl_xor(v, 4));
      v = fmaxf(v, __shfl_xor(v, 8));
      float mn = fmaxf(m_r[r], v);
      alpha[r] = exp2f((m_r[r] - mn) * K1);
      m_r[r] = mn;
      psum[r] = 0.f;
    }
#pragma unroll
    for (int nf = 0; nf < 4; nf++)
#pragma unroll
      for (int r = 0; r < 4; r++) {
        float p = exp2f((sf[nf][r] - m_r[r]) * K1);
        psum[r] += p;
        Ps[w * 16 + quad * 4 + r][nf * 16 + lm] = f2bf(p);
      }
#pragma unroll
    for (int r = 0; r < 4; r++) {
      float v = psum[r];
      v += __shfl_xor(v, 1); v += __shfl_xor(v, 2);
      v += __shfl_xor(v, 4); v += __shfl_xor(v, 8);
      l_r[r] = l_r[r] * alpha[r] + v;
    }
#pragma unroll
    for (int df = 0; df < 8; df++)
#pragma unroll
      for (int r = 0; r < 4; r++) o[df][r] *= alpha[r];
    // O += P V   (P via LDS round-trip: C-layout -> A-layout)
#pragma unroll
    for (int ks = 0; ks < 2; ks++) {
      bf16x8 pf = *(const bf16x8*)(&Ps[w * 16 + lm][ks * 32 + quad * 8]);
#pragma unroll
      for (int df = 0; df < 8; df++) {
        bf16x8 vf = *(const bf16x8*)(&Vt[df * 16 + lm][ks * 32 + quad * 8]);
        o[df] = __builtin_amdgcn_mfma_f32_16x16x32_bf16(pf, vf, o[df], 0, 0, 0);
      }
    }
    __syncthreads();
  }

  float rl[4];
#pragma unroll
  for (int r = 0; r < 4; r++) rl[r] = 1.f / l_r[r];
  int row0 = b * SEQ + qt * 64 + w * 16 + quad * 4;
#pragma unroll
  for (int df = 0; df < 8; df++) {
    int col = h * HEAD_SIZE + df * 16 + lm;
#pragma unroll
    for (int r = 0; r < 4; r++)
      O[(size_t)(row0 + r) * HIDDEN + col] = f2bf(o[df][r] * rl[r]);
  }
}

// ---------------------------------------------------------------- launch
extern "C" void kernel_launch(void* const* d_in, const int* in_sizes, int n_in,
                              void* d_out, int out_size, void* d_ws, size_t ws_size,
                              hipStream_t stream)
{
  const float* hs   = (const float*)d_in[0];
  const float* wqkv = (const float*)d_in[2];
  const float* bqkv = (const float*)d_in[3];
  const float* wd   = (const float*)d_in[4];
  const float* bd   = (const float*)d_in[5];
  const int*   pos  = (const int*)d_in[6];

  // workspace layout (bf16 buffers). attn output aliases hsb (dead after QKV GEMM).
  char* ws = (char*)d_ws;
  unsigned short* hsb = (unsigned short*)ws;  ws += (size_t)TOTAL * HIDDEN * 2;   // 16.8 MB
  unsigned short* wqb = (unsigned short*)ws;  ws += (size_t)QKV_N * HIDDEN * 2;   // 25.2 MB
  unsigned short* wdb = (unsigned short*)ws;  ws += (size_t)HIDDEN * HIDDEN * 2;  //  8.4 MB
  unsigned short* Qb  = (unsigned short*)ws;  ws += (size_t)TOTAL * HIDDEN * 2;
  unsigned short* Kb  = (unsigned short*)ws;  ws += (size_t)TOTAL * HIDDEN * 2;
  unsigned short* Vb  = (unsigned short*)ws;  ws += (size_t)TOTAL * HIDDEN * 2;
  unsigned short* attnb = hsb;
  if (ws_size < (size_t)(ws - (char*)d_ws)) return;  // ~100.7 MB needed

  f32_to_bf16_k<<<TOTAL * HIDDEN / 1024, 256, 0, stream>>>(hs, hsb, TOTAL * HIDDEN);
  f32_to_bf16_k<<<QKV_N * HIDDEN / 1024, 256, 0, stream>>>(wqkv, wqb, QKV_N * HIDDEN);
  f32_to_bf16_k<<<HIDDEN * HIDDEN / 1024, 256, 0, stream>>>(wd, wdb, HIDDEN * HIDDEN);

  gemm_bt<1><<<dim3(QKV_N / 128, TOTAL / 128), 256, 0, stream>>>(
      hsb, wqb, bqkv, nullptr, Qb, Kb, Vb, TOTAL, QKV_N, HIDDEN);

  rotary_k<<<(2 * 64 * SEQ * 16) / 256, 256, 0, stream>>>(Qb, Kb, pos);

  flash_attn_k<<<dim3(SEQ / 64, 64), 256, 0, stream>>>(Qb, Kb, Vb, attnb);

  gemm_bt<0><<<dim3(HIDDEN / 128, TOTAL / 128), 256, 0, stream>>>(
      attnb, wdb, bd, (float*)d_out, nullptr, nullptr, nullptr, TOTAL, HIDDEN, HIDDEN);
}

// Round 2
// 492.442 us; speedup vs baseline: 1.0313x; 1.0313x over previous
//
#include <hip/hip_runtime.h>
#include <stdint.h>

#define NUM_HEADS 16
#define HIDDEN    2048
#define HEAD_SIZE 128
#define TOTAL     4096
#define SEQ       1024
#define QKV_N     (3*HIDDEN)   // 6144

typedef __bf16 bf16x8 __attribute__((ext_vector_type(8)));
typedef float  f32x4  __attribute__((ext_vector_type(4)));

__device__ __forceinline__ unsigned short f2bf(float f) {
  unsigned u = __float_as_uint(f);
  u += 0x7FFFu + ((u >> 16) & 1u);          // RNE
  return (unsigned short)(u >> 16);
}
__device__ __forceinline__ float bf2f(unsigned short h) {
  return __uint_as_float(((unsigned)h) << 16);
}
// async global->LDS, 16B per lane. LDS dest must be wave-uniform base + lane*16.
__device__ __forceinline__ void cp16(void* lds, const void* g) {
  __builtin_amdgcn_global_load_lds(
      (const __attribute__((address_space(1))) void*)g,
      (__attribute__((address_space(3))) void*)lds, 16, 0, 0);
}

// ---------------------------------------------------------------- convert
__global__ __launch_bounds__(256) void f32_to_bf16_k(
    const float* __restrict__ in, unsigned short* __restrict__ out, int n)
{
  int i = (blockIdx.x * 256 + threadIdx.x) * 4;
  if (i >= n) return;
  float4 v = *(const float4*)(in + i);
  unsigned p0 = (unsigned)f2bf(v.x) | ((unsigned)f2bf(v.y) << 16);
  unsigned p1 = (unsigned)f2bf(v.z) | ((unsigned)f2bf(v.w) << 16);
  uint2 pk; pk.x = p0; pk.y = p1;
  *(uint2*)(out + i) = pk;
}

// ---------------------------------------------------------------- GEMM (B^T input)
// C[i,j] = sum_k A[i,k]*B[j,k] + bias[j]
// MODE 0: write float32 to Cf[row*N+col]
// MODE 1: scatter bf16 -> Qb/Kb [B,H,S,D]; V written TRANSPOSED -> Vt [B,H,D,S]
// LDS swizzle: 16B chunk p within a 64B row holds logical chunk p^((row>>1)&3)
// -> frag reads spread over 8 bank windows (2-way, free) instead of 2 (8-way).
template <int MODE>
__global__ __launch_bounds__(256) void gemm_bt(
    const unsigned short* __restrict__ A,   // [M][K] bf16
    const unsigned short* __restrict__ B,   // [N][K] bf16
    const float* __restrict__ bias,         // [N]
    float* __restrict__ Cf,
    unsigned short* __restrict__ Qb,
    unsigned short* __restrict__ Kb,
    unsigned short* __restrict__ Vt,
    int M, int N, int K)
{
  __shared__ unsigned short lsA[128*32];    // 8 KB, row pitch 64B
  __shared__ unsigned short lsB[128*32];
  const int tid  = threadIdx.x;
  const int w    = tid >> 6, lane = tid & 63;
  const int quad = lane >> 4, lm = lane & 15;
  const int wm   = w & 1, wn = w >> 1;
  const int mBase = blockIdx.y * 128;
  const int nBase = blockIdx.x * 128;
  const int swz = (lm >> 1) & 3;            // read-side chunk swizzle (row>>1)&3

  const f32x4 zero4 = {0.f, 0.f, 0.f, 0.f};
  f32x4 acc[4][4];
#pragma unroll
  for (int i = 0; i < 4; i++)
#pragma unroll
    for (int j = 0; j < 4; j++) acc[i][j] = zero4;

  const int cg = ((tid & 3) ^ ((tid >> 3) & 3)) * 16;  // swizzled global 16B chunk

  for (int k0 = 0; k0 < K; k0 += 32) {
#pragma unroll
    for (int i = 0; i < 2; i++) {           // stage A: 128 rows x 64B
      int off = i * 4096 + tid * 16;
      int row = off >> 6;
      cp16((char*)lsA + off, (const char*)(A + (size_t)(mBase + row) * K + k0) + cg);
    }
#pragma unroll
    for (int i = 0; i < 2; i++) {           // stage B
      int off = i * 4096 + tid * 16;
      int row = off >> 6;
      cp16((char*)lsB + off, (const char*)(B + (size_t)(nBase + row) * K + k0) + cg);
    }
    __syncthreads();                         // drains vmcnt -> LDS visible
    bf16x8 af[4], bfr[4];
#pragma unroll
    for (int mf = 0; mf < 4; mf++)
      af[mf] = *(const bf16x8*)(lsA + (wm * 64 + mf * 16 + lm) * 32 + (quad ^ swz) * 8);
#pragma unroll
    for (int nf = 0; nf < 4; nf++)
      bfr[nf] = *(const bf16x8*)(lsB + (wn * 64 + nf * 16 + lm) * 32 + (quad ^ swz) * 8);
#pragma unroll
    for (int mf = 0; mf < 4; mf++)
#pragma unroll
      for (int nf = 0; nf < 4; nf++)
        acc[mf][nf] = __builtin_amdgcn_mfma_f32_16x16x32_bf16(af[mf], bfr[nf], acc[mf][nf], 0, 0, 0);
    __syncthreads();
  }

  // epilogue: C layout col=lane&15, row=quad*4+r (m89-verified)
#pragma unroll
  for (int nf = 0; nf < 4; nf++) {
    int col = nBase + wn * 64 + nf * 16 + lm;
    float bv = bias[col];
    if (MODE == 0) {
#pragma unroll
      for (int mf = 0; mf < 4; mf++) {
        int row0 = mBase + wm * 64 + mf * 16 + quad * 4;
#pragma unroll
        for (int r = 0; r < 4; r++)
          Cf[(size_t)(row0 + r) * N + col] = acc[mf][nf][r] + bv;
      }
    } else {
      int chunk = col >> 7;                  // 128-col chunk = one (head, q/k/v); wave-uniform
      int hh = chunk / 3, t = chunk - 3 * hh;
      int d = col & 127;
      if (t == 2) {                          // V: write transposed [B,H,D,S], 4 s packed / store
#pragma unroll
        for (int mf = 0; mf < 4; mf++) {
          int row0 = mBase + wm * 64 + mf * 16 + quad * 4;
          int b = row0 >> 10, s0 = row0 & 1023;
          unsigned u0 = (unsigned)f2bf(acc[mf][nf][0] + bv) | ((unsigned)f2bf(acc[mf][nf][1] + bv) << 16);
          unsigned u1 = (unsigned)f2bf(acc[mf][nf][2] + bv) | ((unsigned)f2bf(acc[mf][nf][3] + bv) << 16);
          uint2 pk; pk.x = u0; pk.y = u1;
          *(uint2*)(Vt + ((size_t)(b * NUM_HEADS + hh) * HEAD_SIZE + d) * SEQ + s0) = pk;
        }
      } else {
        unsigned short* dst = (t == 0) ? Qb : Kb;
#pragma unroll
        for (int mf = 0; mf < 4; mf++) {
          int row0 = mBase + wm * 64 + mf * 16 + quad * 4;
#pragma unroll
          for (int r = 0; r < 4; r++) {
            int row = row0 + r;
            int b = row >> 10, s = row & 1023;
            dst[((size_t)(b * NUM_HEADS + hh) * SEQ + s) * HEAD_SIZE + d] = f2bf(acc[mf][nf][r] + bv);
          }
        }
      }
    }
  }
}

// ---------------------------------------------------------------- rotary (in place on Q,K)
__global__ __launch_bounds__(256) void rotary_k(
    unsigned short* __restrict__ Qb, unsigned short* __restrict__ Kb,
    const int* __restrict__ pos_ids)
{
  int f = blockIdx.x * 256 + threadIdx.x;    // 2*64*1024*16 = 2^21 threads
  int qk   = f >> 20;
  int rem  = f & 0xFFFFF;
  int bh   = rem >> 14;
  int rem2 = rem & 0x3FFF;
  int s    = rem2 >> 4;
  int i    = rem2 & 15;
  int b    = bh >> 4;
  float pos = (float)pos_ids[b * SEQ + s];
  float inv = exp2f(-0.8304820237f * (float)i);   // 10000^(-i/16)
  float ang = pos * inv, sn, c;
  sincosf(ang, &sn, &c);
  unsigned short* p = (qk ? Kb : Qb) + ((size_t)bh * SEQ + s) * HEAD_SIZE;
  float x1 = bf2f(p[i]);
  float x2 = bf2f(p[i + 16]);
  p[i]      = f2bf(x1 * c - x2 * sn);
  p[i + 16] = f2bf(x1 * sn + x2 * c);
}

// ---------------------------------------------------------------- flash attention
// grid (8 qtiles of 128, 64 bh), 256 threads = 4 waves, wave w owns q-rows w*32..+32
// V comes in pre-transposed [B,H,D,S] -> staged via cp16, no VALU transpose.
__global__ __launch_bounds__(256, 3) void flash_attn_k(
    const unsigned short* __restrict__ Q,
    const unsigned short* __restrict__ K,
    const unsigned short* __restrict__ VT,   // [B,H,D,S]
    unsigned short* __restrict__ O)          // [TOTAL][HIDDEN] bf16
{
  const int qt = blockIdx.x;
  const int bh = blockIdx.y;
  const int b = bh >> 4, h = bh & 15;
  const size_t base = (size_t)bh * SEQ * HEAD_SIZE;
  const unsigned short* Qp = Q + base;
  const unsigned short* Kp = K + base;
  const unsigned short* Vp = VT + base;      // rows are d (128), cols are s (1024)

  __shared__ unsigned short Ks[4][64*32];    // [kchunk][s*32d], 64B pitch, 16 KB
  __shared__ unsigned short Vl[128*64];      // V^T tile [d][64 s], 128B pitch, 16 KB
  __shared__ unsigned short Ps[128][72];     // P [qlocal][s], pitch 144B (pad), 18 KB

  const int tid  = threadIdx.x;
  const int w    = tid >> 6, lane = tid & 63;
  const int quad = lane >> 4, lm = lane & 15;
  const int swz4 = (lm >> 1) & 3;            // Ks read swizzle
  const int swz8 = lm & 7;                   // Vl read swizzle (d&7)

  bf16x8 qf[2][4];
#pragma unroll
  for (int mf = 0; mf < 2; mf++) {
    const unsigned short* qrow = Qp + (size_t)(qt * 128 + w * 32 + mf * 16 + lm) * HEAD_SIZE;
#pragma unroll
    for (int kk = 0; kk < 4; kk++)
      qf[mf][kk] = *(const bf16x8*)(qrow + kk * 32 + quad * 8);
  }
  float m_r[2][4], l_r[2][4];
#pragma unroll
  for (int mf = 0; mf < 2; mf++)
#pragma unroll
    for (int r = 0; r < 4; r++) { m_r[mf][r] = -1e30f; l_r[mf][r] = 0.f; }
  const f32x4 zero4 = {0.f, 0.f, 0.f, 0.f};
  f32x4 o[2][8];
#pragma unroll
  for (int mf = 0; mf < 2; mf++)
#pragma unroll
    for (int i = 0; i < 8; i++) o[mf][i] = zero4;

  const float K1 = 0.1275156876f;            // (1/sqrt(128)) * log2(e)
  const int cgK = ((tid & 3) ^ ((tid >> 3) & 3)) * 8;   // Ks global chunk (u16 elems)
  const int cgV = ((tid & 7) ^ ((tid >> 3) & 7)) * 8;   // Vl global chunk (u16 elems)

  const int ktEnd = 2 * qt + 1;
  for (int kt = 0; kt <= ktEnd; ++kt) {
    // stage K tile (64 s x 128 d), swizzled
    {
      const unsigned short* krow = Kp + (size_t)(kt * 64 + (tid >> 2)) * HEAD_SIZE + cgK;
#pragma unroll
      for (int kk = 0; kk < 4; kk++)
        cp16((char*)&Ks[kk][0] + tid * 16, krow + kk * 32);
    }
    // stage V^T tile (128 d x 64 s), swizzled
#pragma unroll
    for (int i = 0; i < 4; i++) {
      int off = i * 4096 + tid * 16;
      int d = off >> 7;
      cp16((char*)Vl + off, Vp + (size_t)d * SEQ + kt * 64 + cgV);
    }
    __syncthreads();

    // scores + online softmax per 16-row frag
#pragma unroll
    for (int mf = 0; mf < 2; mf++) {
      f32x4 sf[4];
#pragma unroll
      for (int nf = 0; nf < 4; nf++) {
        f32x4 accs = zero4;
#pragma unroll
        for (int kk = 0; kk < 4; kk++) {
          bf16x8 kfrag = *(const bf16x8*)(&Ks[kk][(nf * 16 + lm) * 32 + (quad ^ swz4) * 8]);
          accs = __builtin_amdgcn_mfma_f32_16x16x32_bf16(qf[mf][kk], kfrag, accs, 0, 0, 0);
        }
        sf[nf] = accs;
      }
      int qrow0 = qt * 128 + w * 32 + mf * 16 + quad * 4;
      if (kt >= 2 * qt) {                    // only last two tiles touch the diagonal
#pragma unroll
        for (int nf = 0; nf < 4; nf++) {
          int col = kt * 64 + nf * 16 + lm;
#pragma unroll
          for (int r = 0; r < 4; r++)
            if (col > qrow0 + r) sf[nf][r] = -1e30f;
        }
      }
      float alpha[4], psum[4];
#pragma unroll
      for (int r = 0; r < 4; r++) {
        float v = fmaxf(fmaxf(sf[0][r], sf[1][r]), fmaxf(sf[2][r], sf[3][r]));
        v = fmaxf(v, __shfl_xor(v, 1));
        v = fmaxf(v, __shfl_xor(v, 2));
        v = fmaxf(v, __shfl_xor(v, 4));
        v = fmaxf(v, __shfl_xor(v, 8));
        float mn = fmaxf(m_r[mf][r], v);
        alpha[r] = exp2f((m_r[mf][r] - mn) * K1);
        m_r[mf][r] = mn;
        psum[r] = 0.f;
      }
#pragma unroll
      for (int nf = 0; nf < 4; nf++)
#pragma unroll
        for (int r = 0; r < 4; r++) {
          float p = exp2f((sf[nf][r] - m_r[mf][r]) * K1);
          psum[r] += p;
          Ps[w * 32 + mf * 16 + quad * 4 + r][nf * 16 + lm] = f2bf(p);
        }
#pragma unroll
      for (int r = 0; r < 4; r++) {
        float v = psum[r];
        v += __shfl_xor(v, 1); v += __shfl_xor(v, 2);
        v += __shfl_xor(v, 4); v += __shfl_xor(v, 8);
        l_r[mf][r] = l_r[mf][r] * alpha[r] + v;
      }
#pragma unroll
      for (int df = 0; df < 8; df++)
#pragma unroll
        for (int r = 0; r < 4; r++) o[mf][df][r] *= alpha[r];
    }

    // O += P V : P rows are wave-private (written+read by same wave; lgkmcnt only)
#pragma unroll
    for (int ks = 0; ks < 2; ks++) {
      bf16x8 pf0 = *(const bf16x8*)(&Ps[w * 32 + lm]     [ks * 32 + quad * 8]);
      bf16x8 pf1 = *(const bf16x8*)(&Ps[w * 32 + 16 + lm][ks * 32 + quad * 8]);
#pragma unroll
      for (int df = 0; df < 8; df++) {
        bf16x8 vf = *(const bf16x8*)(&Vl[(df * 16 + lm) * 64 + (((ks * 4 + quad) ^ swz8)) * 8]);
        o[0][df] = __builtin_amdgcn_mfma_f32_16x16x32_bf16(pf0, vf, o[0][df], 0, 0, 0);
        o[1][df] = __builtin_amdgcn_mfma_f32_16x16x32_bf16(pf1, vf, o[1][df], 0, 0, 0);
      }
    }
    __syncthreads();
  }

#pragma unroll
  for (int mf = 0; mf < 2; mf++) {
    float rl[4];
#pragma unroll
    for (int r = 0; r < 4; r++) rl[r] = 1.f / l_r[mf][r];
    int row0 = b * SEQ + qt * 128 + w * 32 + mf * 16 + quad * 4;
#pragma unroll
    for (int df = 0; df < 8; df++) {
      int col = h * HEAD_SIZE + df * 16 + lm;
#pragma unroll
      for (int r = 0; r < 4; r++)
        O[(size_t)(row0 + r) * HIDDEN + col] = f2bf(o[mf][df][r] * rl[r]);
    }
  }
}

// ---------------------------------------------------------------- launch
extern "C" void kernel_launch(void* const* d_in, const int* in_sizes, int n_in,
                              void* d_out, int out_size, void* d_ws, size_t ws_size,
                              hipStream_t stream)
{
  const float* hs   = (const float*)d_in[0];
  const float* wqkv = (const float*)d_in[2];
  const float* bqkv = (const float*)d_in[3];
  const float* wd   = (const float*)d_in[4];
  const float* bd   = (const float*)d_in[5];
  const int*   pos  = (const int*)d_in[6];

  char* ws = (char*)d_ws;
  unsigned short* hsb = (unsigned short*)ws;  ws += (size_t)TOTAL * HIDDEN * 2;   // 16.8 MB
  unsigned short* wqb = (unsigned short*)ws;  ws += (size_t)QKV_N * HIDDEN * 2;   // 25.2 MB
  unsigned short* wdb = (unsigned short*)ws;  ws += (size_t)HIDDEN * HIDDEN * 2;  //  8.4 MB
  unsigned short* Qb  = (unsigned short*)ws;  ws += (size_t)TOTAL * HIDDEN * 2;
  unsigned short* Kb  = (unsigned short*)ws;  ws += (size_t)TOTAL * HIDDEN * 2;
  unsigned short* Vt  = (unsigned short*)ws;  ws += (size_t)TOTAL * HIDDEN * 2;   // [B,H,D,S]
  unsigned short* attnb = hsb;               // hsb dead after QKV GEMM
  if (ws_size < (size_t)(ws - (char*)d_ws)) return;  // ~100.8 MB needed

  f32_to_bf16_k<<<TOTAL * HIDDEN / 1024, 256, 0, stream>>>(hs, hsb, TOTAL * HIDDEN);
  f32_to_bf16_k<<<QKV_N * HIDDEN / 1024, 256, 0, stream>>>(wqkv, wqb, QKV_N * HIDDEN);
  f32_to_bf16_k<<<HIDDEN * HIDDEN / 1024, 256, 0, stream>>>(wd, wdb, HIDDEN * HIDDEN);

  gemm_bt<1><<<dim3(QKV_N / 128, TOTAL / 128), 256, 0, stream>>>(
      hsb, wqb, bqkv, nullptr, Qb, Kb, Vt, TOTAL, QKV_N, HIDDEN);

  rotary_k<<<(2 * 64 * SEQ * 16) / 256, 256, 0, stream>>>(Qb, Kb, pos);

  flash_attn_k<<<dim3(SEQ / 128, 64), 256, 0, stream>>>(Qb, Kb, Vt, attnb);

  gemm_bt<0><<<dim3(HIDDEN / 128, TOTAL / 128), 256, 0, stream>>>(
      attnb, wdb, bd, (float*)d_out, nullptr, nullptr, nullptr, TOTAL, HIDDEN, HIDDEN);
}

// Round 3
// 410.820 us; speedup vs baseline: 1.2362x; 1.1987x over previous
//
#include <hip/hip_runtime.h>
#include <stdint.h>

#define NUM_HEADS 16
#define HIDDEN    2048
#define HEAD_SIZE 128
#define TOTAL     4096
#define SEQ       1024
#define QKV_N     (3*HIDDEN)   // 6144

typedef __bf16 bf16x8 __attribute__((ext_vector_type(8)));
typedef float  f32x4  __attribute__((ext_vector_type(4)));

__device__ __forceinline__ unsigned short f2bf(float f) {
  unsigned u = __float_as_uint(f);
  u += 0x7FFFu + ((u >> 16) & 1u);          // RNE
  return (unsigned short)(u >> 16);
}
__device__ __forceinline__ float bf2f(unsigned short h) {
  return __uint_as_float(((unsigned)h) << 16);
}
// async global->LDS, 16B per lane. LDS dest must be wave-uniform base + lane*16.
__device__ __forceinline__ void cp16(void* lds, const void* g) {
  __builtin_amdgcn_global_load_lds(
      (const __attribute__((address_space(1))) void*)g,
      (__attribute__((address_space(3))) void*)lds, 16, 0, 0);
}

// ---------------------------------------------------------------- convert
__global__ __launch_bounds__(256) void f32_to_bf16_k(
    const float* __restrict__ in, unsigned short* __restrict__ out, int n)
{
  int i = (blockIdx.x * 256 + threadIdx.x) * 4;
  if (i >= n) return;
  float4 v = *(const float4*)(in + i);
  unsigned p0 = (unsigned)f2bf(v.x) | ((unsigned)f2bf(v.y) << 16);
  unsigned p1 = (unsigned)f2bf(v.z) | ((unsigned)f2bf(v.w) << 16);
  uint2 pk; pk.x = p0; pk.y = p1;
  *(uint2*)(out + i) = pk;
}

// ---------------------------------------------------------------- GEMM (B^T input)
// C[i,j] = sum_k A[i,k]*B[j,k] + bias[j]
// MODE 0: write float32 to Cf; MODE 1: scatter bf16 -> Qb/Kb [B,H,S,D], V -> Vt [B,H,D,S]
// LDS 16B-chunk XOR swizzle keeps frag reads at 2-way bank aliasing (free).
template <int MODE>
__global__ __launch_bounds__(256) void gemm_bt(
    const unsigned short* __restrict__ A,   // [M][K] bf16
    const unsigned short* __restrict__ B,   // [N][K] bf16
    const float* __restrict__ bias,         // [N]
    float* __restrict__ Cf,
    unsigned short* __restrict__ Qb,
    unsigned short* __restrict__ Kb,
    unsigned short* __restrict__ Vt,
    int M, int N, int K)
{
  __shared__ unsigned short lsA[128*32];    // 8 KB, row pitch 64B
  __shared__ unsigned short lsB[128*32];
  const int tid  = threadIdx.x;
  const int w    = tid >> 6, lane = tid & 63;
  const int quad = lane >> 4, lm = lane & 15;
  const int wm   = w & 1, wn = w >> 1;
  const int mBase = blockIdx.y * 128;
  const int nBase = blockIdx.x * 128;
  const int swz = (lm >> 1) & 3;            // read-side chunk swizzle (row>>1)&3

  const f32x4 zero4 = {0.f, 0.f, 0.f, 0.f};
  f32x4 acc[4][4];
#pragma unroll
  for (int i = 0; i < 4; i++)
#pragma unroll
    for (int j = 0; j < 4; j++) acc[i][j] = zero4;

  const int cg = ((tid & 3) ^ ((tid >> 3) & 3)) * 16;  // swizzled global 16B chunk

  for (int k0 = 0; k0 < K; k0 += 32) {
#pragma unroll
    for (int i = 0; i < 2; i++) {           // stage A: 128 rows x 64B
      int off = i * 4096 + tid * 16;
      int row = off >> 6;
      cp16((char*)lsA + off, (const char*)(A + (size_t)(mBase + row) * K + k0) + cg);
    }
#pragma unroll
    for (int i = 0; i < 2; i++) {           // stage B
      int off = i * 4096 + tid * 16;
      int row = off >> 6;
      cp16((char*)lsB + off, (const char*)(B + (size_t)(nBase + row) * K + k0) + cg);
    }
    __syncthreads();                         // drains vmcnt -> LDS visible
    bf16x8 af[4], bfr[4];
#pragma unroll
    for (int mf = 0; mf < 4; mf++)
      af[mf] = *(const bf16x8*)(lsA + (wm * 64 + mf * 16 + lm) * 32 + (quad ^ swz) * 8);
#pragma unroll
    for (int nf = 0; nf < 4; nf++)
      bfr[nf] = *(const bf16x8*)(lsB + (wn * 64 + nf * 16 + lm) * 32 + (quad ^ swz) * 8);
#pragma unroll
    for (int mf = 0; mf < 4; mf++)
#pragma unroll
      for (int nf = 0; nf < 4; nf++)
        acc[mf][nf] = __builtin_amdgcn_mfma_f32_16x16x32_bf16(af[mf], bfr[nf], acc[mf][nf], 0, 0, 0);
    __syncthreads();
  }

  // epilogue: C layout col=lane&15, row=quad*4+r (m89-verified)
#pragma unroll
  for (int nf = 0; nf < 4; nf++) {
    int col = nBase + wn * 64 + nf * 16 + lm;
    float bv = bias[col];
    if (MODE == 0) {
#pragma unroll
      for (int mf = 0; mf < 4; mf++) {
        int row0 = mBase + wm * 64 + mf * 16 + quad * 4;
#pragma unroll
        for (int r = 0; r < 4; r++)
          Cf[(size_t)(row0 + r) * N + col] = acc[mf][nf][r] + bv;
      }
    } else {
      int chunk = col >> 7;                  // 128-col chunk = one (head, q/k/v); wave-uniform
      int hh = chunk / 3, t = chunk - 3 * hh;
      int d = col & 127;
      if (t == 2) {                          // V: write transposed [B,H,D,S], 4 s packed / store
#pragma unroll
        for (int mf = 0; mf < 4; mf++) {
          int row0 = mBase + wm * 64 + mf * 16 + quad * 4;
          int b = row0 >> 10, s0 = row0 & 1023;
          unsigned u0 = (unsigned)f2bf(acc[mf][nf][0] + bv) | ((unsigned)f2bf(acc[mf][nf][1] + bv) << 16);
          unsigned u1 = (unsigned)f2bf(acc[mf][nf][2] + bv) | ((unsigned)f2bf(acc[mf][nf][3] + bv) << 16);
          uint2 pk; pk.x = u0; pk.y = u1;
          *(uint2*)(Vt + ((size_t)(b * NUM_HEADS + hh) * HEAD_SIZE + d) * SEQ + s0) = pk;
        }
      } else {
        unsigned short* dst = (t == 0) ? Qb : Kb;
#pragma unroll
        for (int mf = 0; mf < 4; mf++) {
          int row0 = mBase + wm * 64 + mf * 16 + quad * 4;
#pragma unroll
          for (int r = 0; r < 4; r++) {
            int row = row0 + r;
            int b = row >> 10, s = row & 1023;
            dst[((size_t)(b * NUM_HEADS + hh) * SEQ + s) * HEAD_SIZE + d] = f2bf(acc[mf][nf][r] + bv);
          }
        }
      }
    }
  }
}

// ---------------------------------------------------------------- rotary (in place on Q,K)
__global__ __launch_bounds__(256) void rotary_k(
    unsigned short* __restrict__ Qb, unsigned short* __restrict__ Kb,
    const int* __restrict__ pos_ids)
{
  int f = blockIdx.x * 256 + threadIdx.x;    // 2*64*1024*16 = 2^21 threads
  int qk   = f >> 20;
  int rem  = f & 0xFFFFF;
  int bh   = rem >> 14;
  int rem2 = rem & 0x3FFF;
  int s    = rem2 >> 4;
  int i    = rem2 & 15;
  int b    = bh >> 4;
  float pos = (float)pos_ids[b * SEQ + s];
  float inv = exp2f(-0.8304820237f * (float)i);   // 10000^(-i/16)
  float ang = pos * inv, sn, c;
  sincosf(ang, &sn, &c);
  unsigned short* p = (qk ? Kb : Qb) + ((size_t)bh * SEQ + s) * HEAD_SIZE;
  float x1 = bf2f(p[i]);
  float x2 = bf2f(p[i + 16]);
  p[i]      = f2bf(x1 * c - x2 * sn);
  p[i + 16] = f2bf(x1 * sn + x2 * c);
}

// ---------------------------------------------------------------- flash attention
// grid (64 bh, 8 pair). Each block handles Q-tiles qa=15-pair and qb=pair (64 rows each)
// -> exactly 17 k-tile iterations per block (uniform load). Double-buffered K/V staging
// with prefetch issued AFTER the barrier (latency hidden under compute). 4 waves; wave w
// owns q-rows w*16..w*16+15 of the current tile. l computed via MFMA P*ones.
__global__ __launch_bounds__(256, 2) void flash_attn_k(
    const unsigned short* __restrict__ Q,
    const unsigned short* __restrict__ K,
    const unsigned short* __restrict__ VT,   // [B,H,D,S]
    unsigned short* __restrict__ O)          // [TOTAL][HIDDEN] bf16
{
  const int bh = blockIdx.x;                 // bh fastest -> all pairs of a bh on one XCD
  const int pair = blockIdx.y;
  const int qa = 15 - pair, qb = pair;
  const int b = bh >> 4, h = bh & 15;
  const size_t base = (size_t)bh * SEQ * HEAD_SIZE;
  const unsigned short* Qp = Q + base;
  const unsigned short* Kp = K + base;
  const unsigned short* Vp = VT + base;      // [d][s]

  __shared__ unsigned short Ks[2][4][64*32]; // 2 x 16 KB
  __shared__ unsigned short Vl[2][128*64];   // 2 x 16 KB
  __shared__ unsigned short Ps[64][72];      // 9 KB (pitch 144B, 16B-aligned rows)

  const int tid  = threadIdx.x;
  const int w    = tid >> 6, lane = tid & 63;
  const int quad = lane >> 4, lm = lane & 15;
  const int swz4 = (lm >> 1) & 3;            // Ks read swizzle
  const int swz8 = lm & 7;                   // Vl read swizzle (d&7)
  const int cgK = ((tid & 3) ^ ((tid >> 3) & 3)) * 8;   // halves
  const int cgV = ((tid & 7) ^ ((tid >> 3) & 7)) * 8;   // halves

  const float K1 = 0.1275156876f;            // (1/sqrt(128)) * log2(e)
  const f32x4 zero4 = {0.f, 0.f, 0.f, 0.f};
  const __bf16 one = (__bf16)1.0f;
  const bf16x8 vones = {one, one, one, one, one, one, one, one};

  auto stage = [&](int buf, int kt) {
    const unsigned short* krow = Kp + (size_t)(kt * 64 + (tid >> 2)) * HEAD_SIZE + cgK;
#pragma unroll
    for (int kk = 0; kk < 4; kk++)
      cp16((char*)&Ks[buf][kk][0] + tid * 16, krow + kk * 32);
#pragma unroll
    for (int i = 0; i < 4; i++) {
      int off = i * 4096 + tid * 16;
      int d = off >> 7;
      cp16((char*)&Vl[buf][0] + off, Vp + (size_t)d * SEQ + kt * 64 + cgV);
    }
  };

  int buf = 0;
  stage(0, 0);

  for (int ph = 0; ph < 2; ph++) {
    const int qt = ph ? qb : qa;
    bf16x8 qf[4];
    {
      const unsigned short* qrow = Qp + (size_t)(qt * 64 + w * 16 + lm) * HEAD_SIZE;
#pragma unroll
      for (int kk = 0; kk < 4; kk++)
        qf[kk] = *(const bf16x8*)(qrow + kk * 32 + quad * 8);
    }
    float m_r[4];
#pragma unroll
    for (int r = 0; r < 4; r++) m_r[r] = -1e30f;
    f32x4 lacc = zero4;
    f32x4 o[8];
#pragma unroll
    for (int i = 0; i < 8; i++) o[i] = zero4;

    for (int kt = 0; kt <= qt; ++kt) {
      __syncthreads();                       // staging of `buf` landed; buf^1 free
      bool last = (ph == 1) && (kt == qt);
      if (!last) stage(buf ^ 1, (kt < qt) ? kt + 1 : 0);   // prefetch (drained at NEXT barrier)

      // S = Q K^T
      f32x4 sf[4];
#pragma unroll
      for (int nf = 0; nf < 4; nf++) {
        f32x4 accs = zero4;
#pragma unroll
        for (int kk = 0; kk < 4; kk++) {
          bf16x8 kfrag = *(const bf16x8*)(&Ks[buf][kk][(nf * 16 + lm) * 32 + (quad ^ swz4) * 8]);
          accs = __builtin_amdgcn_mfma_f32_16x16x32_bf16(qf[kk], kfrag, accs, 0, 0, 0);
        }
        sf[nf] = accs;
      }
      if (kt == qt) {                        // diagonal tile: causal mask
        int qrow0 = qt * 64 + w * 16 + quad * 4;
#pragma unroll
        for (int nf = 0; nf < 4; nf++) {
          int col = kt * 64 + nf * 16 + lm;
#pragma unroll
          for (int r = 0; r < 4; r++)
            if (col > qrow0 + r) sf[nf][r] = -1e30f;
        }
      }
      // online softmax: row max across 16 lanes, alpha rescale
      float alpha[4];
#pragma unroll
      for (int r = 0; r < 4; r++) {
        float v = fmaxf(fmaxf(sf[0][r], sf[1][r]), fmaxf(sf[2][r], sf[3][r]));
        v = fmaxf(v, __shfl_xor(v, 1));
        v = fmaxf(v, __shfl_xor(v, 2));
        v = fmaxf(v, __shfl_xor(v, 4));
        v = fmaxf(v, __shfl_xor(v, 8));
        float mn = fmaxf(m_r[r], v);
        alpha[r] = exp2f((m_r[r] - mn) * K1);
        m_r[r] = mn;
      }
#pragma unroll
      for (int nf = 0; nf < 4; nf++)
#pragma unroll
        for (int r = 0; r < 4; r++) {
          float p = exp2f((sf[nf][r] - m_r[r]) * K1);
          Ps[w * 16 + quad * 4 + r][nf * 16 + lm] = f2bf(p);
        }
#pragma unroll
      for (int df = 0; df < 8; df++)
#pragma unroll
        for (int r = 0; r < 4; r++) o[df][r] *= alpha[r];
#pragma unroll
      for (int r = 0; r < 4; r++) lacc[r] *= alpha[r];

      // O += P V ; l += P * 1   (P rows wave-private: lgkmcnt-only hazard)
#pragma unroll
      for (int ks = 0; ks < 2; ks++) {
        bf16x8 pf = *(const bf16x8*)(&Ps[w * 16 + lm][ks * 32 + quad * 8]);
        lacc = __builtin_amdgcn_mfma_f32_16x16x32_bf16(pf, vones, lacc, 0, 0, 0);
#pragma unroll
        for (int df = 0; df < 8; df++) {
          bf16x8 vf = *(const bf16x8*)(&Vl[buf][(df * 16 + lm) * 64 + (((ks * 4 + quad) ^ swz8)) * 8]);
          o[df] = __builtin_amdgcn_mfma_f32_16x16x32_bf16(pf, vf, o[df], 0, 0, 0);
        }
      }
      buf ^= 1;
    }

    // finalize this Q-tile
    float rl[4];
#pragma unroll
    for (int r = 0; r < 4; r++) rl[r] = 1.f / lacc[r];
    int row0 = b * SEQ + qt * 64 + w * 16 + quad * 4;
#pragma unroll
    for (int df = 0; df < 8; df++) {
      int col = h * HEAD_SIZE + df * 16 + lm;
#pragma unroll
      for (int r = 0; r < 4; r++)
        O[(size_t)(row0 + r) * HIDDEN + col] = f2bf(o[df][r] * rl[r]);
    }
  }
}

// ---------------------------------------------------------------- launch
extern "C" void kernel_launch(void* const* d_in, const int* in_sizes, int n_in,
                              void* d_out, int out_size, void* d_ws, size_t ws_size,
                              hipStream_t stream)
{
  const float* hs   = (const float*)d_in[0];
  const float* wqkv = (const float*)d_in[2];
  const float* bqkv = (const float*)d_in[3];
  const float* wd   = (const float*)d_in[4];
  const float* bd   = (const float*)d_in[5];
  const int*   pos  = (const int*)d_in[6];

  char* ws = (char*)d_ws;
  unsigned short* hsb = (unsigned short*)ws;  ws += (size_t)TOTAL * HIDDEN * 2;   // 16.8 MB
  unsigned short* wqb = (unsigned short*)ws;  ws += (size_t)QKV_N * HIDDEN * 2;   // 25.2 MB
  unsigned short* wdb = (unsigned short*)ws;  ws += (size_t)HIDDEN * HIDDEN * 2;  //  8.4 MB
  unsigned short* Qb  = (unsigned short*)ws;  ws += (size_t)TOTAL * HIDDEN * 2;
  unsigned short* Kb  = (unsigned short*)ws;  ws += (size_t)TOTAL * HIDDEN * 2;
  unsigned short* Vt  = (unsigned short*)ws;  ws += (size_t)TOTAL * HIDDEN * 2;   // [B,H,D,S]
  unsigned short* attnb = hsb;               // hsb dead after QKV GEMM
  if (ws_size < (size_t)(ws - (char*)d_ws)) return;  // ~100.8 MB needed

  f32_to_bf16_k<<<TOTAL * HIDDEN / 1024, 256, 0, stream>>>(hs, hsb, TOTAL * HIDDEN);
  f32_to_bf16_k<<<QKV_N * HIDDEN / 1024, 256, 0, stream>>>(wqkv, wqb, QKV_N * HIDDEN);
  f32_to_bf16_k<<<HIDDEN * HIDDEN / 1024, 256, 0, stream>>>(wd, wdb, HIDDEN * HIDDEN);

  gemm_bt<1><<<dim3(QKV_N / 128, TOTAL / 128), 256, 0, stream>>>(
      hsb, wqb, bqkv, nullptr, Qb, Kb, Vt, TOTAL, QKV_N, HIDDEN);

  rotary_k<<<(2 * 64 * SEQ * 16) / 256, 256, 0, stream>>>(Qb, Kb, pos);

  flash_attn_k<<<dim3(64, 8), 256, 0, stream>>>(Qb, Kb, Vt, attnb);

  gemm_bt<0><<<dim3(HIDDEN / 128, TOTAL / 128), 256, 0, stream>>>(
      attnb, wdb, bd, (float*)d_out, nullptr, nullptr, nullptr, TOTAL, HIDDEN, HIDDEN);
}

// Round 4
// 386.255 us; speedup vs baseline: 1.3148x; 1.0636x over previous
//
#include <hip/hip_runtime.h>
#include <stdint.h>

#define NUM_HEADS 16
#define HIDDEN    2048
#define HEAD_SIZE 128
#define TOTAL     4096
#define SEQ       1024
#define QKV_N     (3*HIDDEN)   // 6144

typedef __bf16 bf16x8 __attribute__((ext_vector_type(8)));
typedef float  f32x4  __attribute__((ext_vector_type(4)));

__device__ __forceinline__ unsigned short f2bf(float f) {
  unsigned u = __float_as_uint(f);
  u += 0x7FFFu + ((u >> 16) & 1u);          // RNE
  return (unsigned short)(u >> 16);
}
__device__ __forceinline__ float bf2f(unsigned short h) {
  return __uint_as_float(((unsigned)h) << 16);
}
// async global->LDS, 16B per lane. LDS dest must be wave-uniform base + lane*16.
__device__ __forceinline__ void cp16(void* lds, const void* g) {
  __builtin_amdgcn_global_load_lds(
      (const __attribute__((address_space(1))) void*)g,
      (__attribute__((address_space(3))) void*)lds, 16, 0, 0);
}

// ---------------------------------------------------------------- fused convert (3 tensors)
__global__ __launch_bounds__(256) void f32_to_bf16_multi(
    const float* __restrict__ a, unsigned short* __restrict__ oa, int na,
    const float* __restrict__ b, unsigned short* __restrict__ ob, int nb,
    const float* __restrict__ c, unsigned short* __restrict__ oc, int nc)
{
  int i = (blockIdx.x * 256 + threadIdx.x) * 4;
  const float* src; unsigned short* dst;
  if (i < na)            { src = a; dst = oa; }
  else if (i < na + nb)  { i -= na; src = b; dst = ob; }
  else                   { i -= na + nb; if (i >= nc) return; src = c; dst = oc; }
  float4 v = *(const float4*)(src + i);
  unsigned p0 = (unsigned)f2bf(v.x) | ((unsigned)f2bf(v.y) << 16);
  unsigned p1 = (unsigned)f2bf(v.z) | ((unsigned)f2bf(v.w) << 16);
  uint2 pk; pk.x = p0; pk.y = p1;
  *(uint2*)(dst + i) = pk;
}

// ---------------------------------------------------------------- GEMM (B^T input), dbuf K-loop
// C[i,j] = sum_k A[i,k]*B[j,k] + bias[j]
// MODE 0: write float32 to Cf
// MODE 1: scatter bf16 -> Qb/Kb [B,H,S,D] WITH FUSED ROTARY on d<32 of Q,K; V -> Vt [B,H,D,S]
// Double-buffered LDS: ONE barrier per 32-K step; prefetch issued after this step's frag
// ds_reads (no ds_read follows a cp16 inside an iteration -> no conservative vmcnt wait).
// 16B-chunk XOR swizzle keeps frag reads at 2-way bank aliasing (free).
template <int MODE>
__global__ __launch_bounds__(256) void gemm_bt(
    const unsigned short* __restrict__ A,   // [M][K] bf16
    const unsigned short* __restrict__ B,   // [N][K] bf16
    const float* __restrict__ bias,         // [N]
    const int* __restrict__ pos_ids,        // [TOTAL] (MODE 1 only)
    float* __restrict__ Cf,
    unsigned short* __restrict__ Qb,
    unsigned short* __restrict__ Kb,
    unsigned short* __restrict__ Vt,
    int M, int N, int K)
{
  __shared__ unsigned short lsA[2][128*32]; // 2 x 8 KB, row pitch 64B
  __shared__ unsigned short lsB[2][128*32];
  const int tid  = threadIdx.x;
  const int w    = tid >> 6, lane = tid & 63;
  const int quad = lane >> 4, lm = lane & 15;
  const int wm   = w & 1, wn = w >> 1;
  const int mBase = blockIdx.y * 128;
  const int nBase = blockIdx.x * 128;
  const int swz = (lm >> 1) & 3;            // read-side chunk swizzle (row>>1)&3

  const f32x4 zero4 = {0.f, 0.f, 0.f, 0.f};
  f32x4 acc[4][4];
#pragma unroll
  for (int i = 0; i < 4; i++)
#pragma unroll
    for (int j = 0; j < 4; j++) acc[i][j] = zero4;

  const int cg = ((tid & 3) ^ ((tid >> 3) & 3)) * 16;  // swizzled global 16B chunk
  const int srow = tid >> 2;                           // staging row owned by this thread pair-of-16B... (off>>6)

  // staging: 128 rows x 64B per matrix; thread t covers bytes [t*16, t*16+16) of the 8KB tile
  auto stage = [&](int bufi, int k0) {
#pragma unroll
    for (int i = 0; i < 2; i++) {
      int off = i * 4096 + tid * 16;
      int row = off >> 6;
      cp16((char*)&lsA[bufi][0] + off, (const char*)(A + (size_t)(mBase + row) * K + k0) + cg);
    }
#pragma unroll
    for (int i = 0; i < 2; i++) {
      int off = i * 4096 + tid * 16;
      int row = off >> 6;
      cp16((char*)&lsB[bufi][0] + off, (const char*)(B + (size_t)(nBase + row) * K + k0) + cg);
    }
  };

  int buf = 0;
  stage(0, 0);

  for (int k0 = 0; k0 < K; k0 += 32) {
    __syncthreads();                         // drains prefetch of `buf` (vmcnt0) + prev reads (lgkm0)
    bf16x8 af[4], bfr[4];
#pragma unroll
    for (int mf = 0; mf < 4; mf++)
      af[mf] = *(const bf16x8*)(&lsA[buf][(wm * 64 + mf * 16 + lm) * 32 + (quad ^ swz) * 8]);
#pragma unroll
    for (int nf = 0; nf < 4; nf++)
      bfr[nf] = *(const bf16x8*)(&lsB[buf][(wn * 64 + nf * 16 + lm) * 32 + (quad ^ swz) * 8]);
    if (k0 + 32 < K) stage(buf ^ 1, k0 + 32);   // prefetch; lands by NEXT barrier
#pragma unroll
    for (int mf = 0; mf < 4; mf++)
#pragma unroll
      for (int nf = 0; nf < 4; nf++)
        acc[mf][nf] = __builtin_amdgcn_mfma_f32_16x16x32_bf16(af[mf], bfr[nf], acc[mf][nf], 0, 0, 0);
    buf ^= 1;
  }

  // epilogue: C layout col=lane&15, row=quad*4+r (m89-verified)
  if (MODE == 0) {
#pragma unroll
    for (int nf = 0; nf < 4; nf++) {
      int col = nBase + wn * 64 + nf * 16 + lm;
      float bv = bias[col];
#pragma unroll
      for (int mf = 0; mf < 4; mf++) {
        int row0 = mBase + wm * 64 + mf * 16 + quad * 4;
#pragma unroll
        for (int r = 0; r < 4; r++)
          Cf[(size_t)(row0 + r) * N + col] = acc[mf][nf][r] + bv;
      }
    }
  } else {
    const int col0 = nBase + wn * 64;        // wave-uniform 64-col window
    const int chunk = col0 >> 7;             // (head, q/k/v)
    const int hh = chunk / 3, t = chunk - 3 * hh;
    const bool lower = ((col0 >> 6) & 1) == 0;   // d in [0,64) vs [64,128)
    if (t == 2) {                            // V: write transposed [B,H,D,S], 4 s packed / store
#pragma unroll
      for (int nf = 0; nf < 4; nf++) {
        int col = col0 + nf * 16 + lm;
        float bv = bias[col];
        int d = col & 127;
#pragma unroll
        for (int mf = 0; mf < 4; mf++) {
          int row0 = mBase + wm * 64 + mf * 16 + quad * 4;
          int b = row0 >> 10, s0 = row0 & 1023;
          unsigned u0 = (unsigned)f2bf(acc[mf][nf][0] + bv) | ((unsigned)f2bf(acc[mf][nf][1] + bv) << 16);
          unsigned u1 = (unsigned)f2bf(acc[mf][nf][2] + bv) | ((unsigned)f2bf(acc[mf][nf][3] + bv) << 16);
          uint2 pk; pk.x = u0; pk.y = u1;
          *(uint2*)(Vt + ((size_t)(b * NUM_HEADS + hh) * HEAD_SIZE + d) * SEQ + s0) = pk;
        }
      }
    } else {
      unsigned short* dst = (t == 0) ? Qb : Kb;
      if (lower) {
        // nf=0 (d=lm) pairs with nf=1 (d=lm+16): fused NeoX rotary. nf=2,3 pass-through.
        const float inv = exp2f(-0.8304820237f * (float)lm);   // 10000^(-lm/16)
        const float bv0 = bias[col0 + lm];
        const float bv1 = bias[col0 + 16 + lm];
#pragma unroll
        for (int mf = 0; mf < 4; mf++) {
          int row0 = mBase + wm * 64 + mf * 16 + quad * 4;
#pragma unroll
          for (int r = 0; r < 4; r++) {
            int row = row0 + r;
            int b = row >> 10, s = row & 1023;
            float pos = (float)pos_ids[row];
            float sn, cs;
            sincosf(pos * inv, &sn, &cs);
            float x1 = acc[mf][0][r] + bv0;
            float x2 = acc[mf][1][r] + bv1;
            size_t rb = ((size_t)(b * NUM_HEADS + hh) * SEQ + s) * HEAD_SIZE;
            dst[rb + lm]      = f2bf(x1 * cs - x2 * sn);
            dst[rb + 16 + lm] = f2bf(x1 * sn + x2 * cs);
          }
        }
#pragma unroll
        for (int nf = 2; nf < 4; nf++) {
          float bv = bias[col0 + nf * 16 + lm];
          int d = nf * 16 + lm;
#pragma unroll
          for (int mf = 0; mf < 4; mf++) {
            int row0 = mBase + wm * 64 + mf * 16 + quad * 4;
#pragma unroll
            for (int r = 0; r < 4; r++) {
              int row = row0 + r;
              int b = row >> 10, s = row & 1023;
              dst[((size_t)(b * NUM_HEADS + hh) * SEQ + s) * HEAD_SIZE + d] = f2bf(acc[mf][nf][r] + bv);
            }
          }
        }
      } else {
#pragma unroll
        for (int nf = 0; nf < 4; nf++) {
          float bv = bias[col0 + nf * 16 + lm];
          int d = 64 + nf * 16 + lm;
#pragma unroll
          for (int mf = 0; mf < 4; mf++) {
            int row0 = mBase + wm * 64 + mf * 16 + quad * 4;
#pragma unroll
            for (int r = 0; r < 4; r++) {
              int row = row0 + r;
              int b = row >> 10, s = row & 1023;
              dst[((size_t)(b * NUM_HEADS + hh) * SEQ + s) * HEAD_SIZE + d] = f2bf(acc[mf][nf][r] + bv);
            }
          }
        }
      }
    }
  }
}

// ---------------------------------------------------------------- flash attention (UNCHANGED r3)
// grid (64 bh, 8 pair). Each block handles Q-tiles qa=15-pair and qb=pair (64 rows each)
// -> exactly 17 k-tile iterations per block (uniform load). Double-buffered K/V staging
// with prefetch issued AFTER the barrier. 4 waves; wave w owns q-rows w*16..w*16+15.
__global__ __launch_bounds__(256, 2) void flash_attn_k(
    const unsigned short* __restrict__ Q,
    const unsigned short* __restrict__ K,
    const unsigned short* __restrict__ VT,   // [B,H,D,S]
    unsigned short* __restrict__ O)          // [TOTAL][HIDDEN] bf16
{
  const int bh = blockIdx.x;                 // linear-id % 8 == bh % 8 -> pairs of a bh share an XCD
  const int pair = blockIdx.y;
  const int qa = 15 - pair, qb = pair;
  const int b = bh >> 4, h = bh & 15;
  const size_t base = (size_t)bh * SEQ * HEAD_SIZE;
  const unsigned short* Qp = Q + base;
  const unsigned short* Kp = K + base;
  const unsigned short* Vp = VT + base;      // [d][s]

  __shared__ unsigned short Ks[2][4][64*32]; // 2 x 16 KB
  __shared__ unsigned short Vl[2][128*64];   // 2 x 16 KB
  __shared__ unsigned short Ps[64][72];      // 9 KB (pitch 144B, 16B-aligned rows)

  const int tid  = threadIdx.x;
  const int w    = tid >> 6, lane = tid & 63;
  const int quad = lane >> 4, lm = lane & 15;
  const int swz4 = (lm >> 1) & 3;            // Ks read swizzle
  const int swz8 = lm & 7;                   // Vl read swizzle (d&7)
  const int cgK = ((tid & 3) ^ ((tid >> 3) & 3)) * 8;   // halves
  const int cgV = ((tid & 7) ^ ((tid >> 3) & 7)) * 8;   // halves

  const float K1 = 0.1275156876f;            // (1/sqrt(128)) * log2(e)
  const f32x4 zero4 = {0.f, 0.f, 0.f, 0.f};
  const __bf16 one = (__bf16)1.0f;
  const bf16x8 vones = {one, one, one, one, one, one, one, one};

  auto stage = [&](int buf, int kt) {
    const unsigned short* krow = Kp + (size_t)(kt * 64 + (tid >> 2)) * HEAD_SIZE + cgK;
#pragma unroll
    for (int kk = 0; kk < 4; kk++)
      cp16((char*)&Ks[buf][kk][0] + tid * 16, krow + kk * 32);
#pragma unroll
    for (int i = 0; i < 4; i++) {
      int off = i * 4096 + tid * 16;
      int d = off >> 7;
      cp16((char*)&Vl[buf][0] + off, Vp + (size_t)d * SEQ + kt * 64 + cgV);
    }
  };

  int buf = 0;
  stage(0, 0);

  for (int ph = 0; ph < 2; ph++) {
    const int qt = ph ? qb : qa;
    bf16x8 qf[4];
    {
      const unsigned short* qrow = Qp + (size_t)(qt * 64 + w * 16 + lm) * HEAD_SIZE;
#pragma unroll
      for (int kk = 0; kk < 4; kk++)
        qf[kk] = *(const bf16x8*)(qrow + kk * 32 + quad * 8);
    }
    float m_r[4];
#pragma unroll
    for (int r = 0; r < 4; r++) m_r[r] = -1e30f;
    f32x4 lacc = zero4;
    f32x4 o[8];
#pragma unroll
    for (int i = 0; i < 8; i++) o[i] = zero4;

    for (int kt = 0; kt <= qt; ++kt) {
      __syncthreads();                       // staging of `buf` landed; buf^1 free
      bool last = (ph == 1) && (kt == qt);
      if (!last) stage(buf ^ 1, (kt < qt) ? kt + 1 : 0);   // prefetch (drained at NEXT barrier)

      // S = Q K^T
      f32x4 sf[4];
#pragma unroll
      for (int nf = 0; nf < 4; nf++) {
        f32x4 accs = zero4;
#pragma unroll
        for (int kk = 0; kk < 4; kk++) {
          bf16x8 kfrag = *(const bf16x8*)(&Ks[buf][kk][(nf * 16 + lm) * 32 + (quad ^ swz4) * 8]);
          accs = __builtin_amdgcn_mfma_f32_16x16x32_bf16(qf[kk], kfrag, accs, 0, 0, 0);
        }
        sf[nf] = accs;
      }
      if (kt == qt) {                        // diagonal tile: causal mask
        int qrow0 = qt * 64 + w * 16 + quad * 4;
#pragma unroll
        for (int nf = 0; nf < 4; nf++) {
          int col = kt * 64 + nf * 16 + lm;
#pragma unroll
          for (int r = 0; r < 4; r++)
            if (col > qrow0 + r) sf[nf][r] = -1e30f;
        }
      }
      // online softmax: row max across 16 lanes, alpha rescale
      float alpha[4];
#pragma unroll
      for (int r = 0; r < 4; r++) {
        float v = fmaxf(fmaxf(sf[0][r], sf[1][r]), fmaxf(sf[2][r], sf[3][r]));
        v = fmaxf(v, __shfl_xor(v, 1));
        v = fmaxf(v, __shfl_xor(v, 2));
        v = fmaxf(v, __shfl_xor(v, 4));
        v = fmaxf(v, __shfl_xor(v, 8));
        float mn = fmaxf(m_r[r], v);
        alpha[r] = exp2f((m_r[r] - mn) * K1);
        m_r[r] = mn;
      }
#pragma unroll
      for (int nf = 0; nf < 4; nf++)
#pragma unroll
        for (int r = 0; r < 4; r++) {
          float p = exp2f((sf[nf][r] - m_r[r]) * K1);
          Ps[w * 16 + quad * 4 + r][nf * 16 + lm] = f2bf(p);
        }
#pragma unroll
      for (int df = 0; df < 8; df++)
#pragma unroll
        for (int r = 0; r < 4; r++) o[df][r] *= alpha[r];
#pragma unroll
      for (int r = 0; r < 4; r++) lacc[r] *= alpha[r];

      // O += P V ; l += P * 1   (P rows wave-private: lgkmcnt-only hazard)
#pragma unroll
      for (int ks = 0; ks < 2; ks++) {
        bf16x8 pf = *(const bf16x8*)(&Ps[w * 16 + lm][ks * 32 + quad * 8]);
        lacc = __builtin_amdgcn_mfma_f32_16x16x32_bf16(pf, vones, lacc, 0, 0, 0);
#pragma unroll
        for (int df = 0; df < 8; df++) {
          bf16x8 vf = *(const bf16x8*)(&Vl[buf][(df * 16 + lm) * 64 + (((ks * 4 + quad) ^ swz8)) * 8]);
          o[df] = __builtin_amdgcn_mfma_f32_16x16x32_bf16(pf, vf, o[df], 0, 0, 0);
        }
      }
      buf ^= 1;
    }

    // finalize this Q-tile
    float rl[4];
#pragma unroll
    for (int r = 0; r < 4; r++) rl[r] = 1.f / lacc[r];
    int row0 = b * SEQ + qt * 64 + w * 16 + quad * 4;
#pragma unroll
    for (int df = 0; df < 8; df++) {
      int col = h * HEAD_SIZE + df * 16 + lm;
#pragma unroll
      for (int r = 0; r < 4; r++)
        O[(size_t)(row0 + r) * HIDDEN + col] = f2bf(o[df][r] * rl[r]);
    }
  }
}

// ---------------------------------------------------------------- launch
extern "C" void kernel_launch(void* const* d_in, const int* in_sizes, int n_in,
                              void* d_out, int out_size, void* d_ws, size_t ws_size,
                              hipStream_t stream)
{
  const float* hs   = (const float*)d_in[0];
  const float* wqkv = (const float*)d_in[2];
  const float* bqkv = (const float*)d_in[3];
  const float* wd   = (const float*)d_in[4];
  const float* bd   = (const float*)d_in[5];
  const int*   pos  = (const int*)d_in[6];

  char* ws = (char*)d_ws;
  unsigned short* hsb = (unsigned short*)ws;  ws += (size_t)TOTAL * HIDDEN * 2;   // 16.8 MB
  unsigned short* wqb = (unsigned short*)ws;  ws += (size_t)QKV_N * HIDDEN * 2;   // 25.2 MB
  unsigned short* wdb = (unsigned short*)ws;  ws += (size_t)HIDDEN * HIDDEN * 2;  //  8.4 MB
  unsigned short* Qb  = (unsigned short*)ws;  ws += (size_t)TOTAL * HIDDEN * 2;
  unsigned short* Kb  = (unsigned short*)ws;  ws += (size_t)TOTAL * HIDDEN * 2;
  unsigned short* Vt  = (unsigned short*)ws;  ws += (size_t)TOTAL * HIDDEN * 2;   // [B,H,D,S]
  unsigned short* attnb = hsb;               // hsb dead after QKV GEMM
  if (ws_size < (size_t)(ws - (char*)d_ws)) return;  // ~100.8 MB needed

  const int na = TOTAL * HIDDEN, nb = QKV_N * HIDDEN, nc = HIDDEN * HIDDEN;
  f32_to_bf16_multi<<<(na + nb + nc) / 1024, 256, 0, stream>>>(
      hs, hsb, na, wqkv, wqb, nb, wd, wdb, nc);

  gemm_bt<1><<<dim3(QKV_N / 128, TOTAL / 128), 256, 0, stream>>>(
      hsb, wqb, bqkv, pos, nullptr, Qb, Kb, Vt, TOTAL, QKV_N, HIDDEN);

  flash_attn_k<<<dim3(64, 8), 256, 0, stream>>>(Qb, Kb, Vt, attnb);

  gemm_bt<0><<<dim3(HIDDEN / 128, TOTAL / 128), 256, 0, stream>>>(
      attnb, wdb, bd, pos, (float*)d_out, nullptr, nullptr, nullptr, TOTAL, HIDDEN, HIDDEN);
}